// Round 11
// baseline (120.728 us; speedup 1.0000x reference)
//
#include <hip/hip_runtime.h>
#include <hip/hip_bf16.h>
#include <stdint.h>

#define FEAT 1024
#define NALL 1000
#define NCLS 100

typedef __attribute__((ext_vector_type(8))) short short8;
typedef __attribute__((ext_vector_type(4))) float f32x4;
typedef __attribute__((ext_vector_type(4))) unsigned short us4;

__device__ __forceinline__ unsigned short f2bf(float f) {
    union { float f; uint32_t u; } v; v.f = f;
    uint32_t u = v.u;
    return (unsigned short)((u + 0x7FFFu + ((u >> 16) & 1u)) >> 16);
}

__device__ __forceinline__ void gload16(const void* g, void* l) {
    __builtin_amdgcn_global_load_lds((__attribute__((address_space(1))) void*)g,
                                     (__attribute__((address_space(3))) void*)l,
                                     16, 0, 0);
}

// K1: x (16384x1024 f32) -> bf16, plus row sum-of-squares
__global__ __launch_bounds__(256) void k_prep_x(const float* __restrict__ x,
                                                unsigned short* __restrict__ xb,
                                                float* __restrict__ xsq) {
    int row = blockIdx.x * 4 + (threadIdx.x >> 6);
    int lane = threadIdx.x & 63;
    const float4* xr = (const float4*)(x + (size_t)row * FEAT);
    float s = 0.f;
#pragma unroll
    for (int i = 0; i < 4; ++i) {
        float4 v = xr[lane + i * 64];
        s += v.x * v.x + v.y * v.y + v.z * v.z + v.w * v.w;
        us4 o;
        o[0] = f2bf(v.x); o[1] = f2bf(v.y); o[2] = f2bf(v.z); o[3] = f2bf(v.w);
        *(us4*)(xb + (size_t)row * FEAT + (size_t)(lane + i * 64) * 4) = o;
    }
#pragma unroll
    for (int off = 32; off; off >>= 1) s += __shfl_xor(s, off);
    if (lane == 0) xsq[row] = s;
}

// K2a: enc_w (1024x1024 f32) -> transposed bf16 (wt[n][k] = enc_w[k][n])
__global__ __launch_bounds__(256) void k_transpose_w(const float* __restrict__ w,
                                                     unsigned short* __restrict__ wt) {
    __shared__ float tile[32][33];
    int bx = blockIdx.x, by = blockIdx.y;
    int tx = threadIdx.x & 31, ty = threadIdx.x >> 5;
#pragma unroll
    for (int i = 0; i < 4; ++i) {
        int r = by * 32 + ty + i * 8;
        tile[ty + i * 8][tx] = w[(size_t)r * FEAT + bx * 32 + tx];
    }
    __syncthreads();
#pragma unroll
    for (int i = 0; i < 4; ++i) {
        int r = bx * 32 + ty + i * 8;
        wt[(size_t)r * FEAT + by * 32 + tx] = f2bf(tile[tx][ty + i * 8]);
    }
}

// K2b (FUSED): encoder GEMM ep = protos @ enc_w + b.
//  - A staged directly from protos f32 (row-guarded, ds_write) — kills k_prep_protos
//  - B staged from wtb bf16 via global_load_lds (unchanged layout)
//  - epilogue: permuted class-major write n' = (n%100)*10 + n/100, PLUS
//    psq partial sums via lf-lane shfl reduction + one atomicAdd per row-block
//    (kills k_psq; psq is zeroed by memsetAsync before this kernel).
__global__ __launch_bounds__(256) void k_enc(const float* __restrict__ protos,
                                             const unsigned short* __restrict__ B,
                                             const float* __restrict__ bias,
                                             unsigned short* __restrict__ epb,
                                             float* __restrict__ psq) {
    __shared__ __align__(16) char smem[32768];
    int bm0 = (blockIdx.x >> 3) * 128;
    int bn0 = (blockIdx.x & 7) * 128;
    int tid = threadIdx.x, lane = tid & 63, wid = tid >> 6;
    int wm = wid >> 1, wn = wid & 1;
    int ls = lane >> 4, lf = lane & 15;

    // A-stage addressing: thread t covers row t>>1, col half (t&1)*32
    const int er = tid >> 1;
    const bool ev = (bm0 + er) < NALL;
    const float* ap = protos + (size_t)(bm0 + er) * FEAT + (tid & 1) * 32;
    us4* ad = (us4*)smem + er * 16 + (tid & 1) * 8;   // LDS A [128][64] bf16

    f32x4 acc[4][4] = {};
    for (int k0 = 0; k0 < FEAT; k0 += 64) {
        __syncthreads();
        // A: protos f32 -> bf16 LDS (zero pad rows)
#pragma unroll
        for (int i = 0; i < 8; ++i) {
            float4 v = ev ? *(const float4*)(ap + k0 + i * 4)
                          : make_float4(0.f, 0.f, 0.f, 0.f);
            us4 o;
            o[0] = f2bf(v.x); o[1] = f2bf(v.y); o[2] = f2bf(v.z); o[3] = f2bf(v.w);
            ad[i] = o;
        }
        // B: wtb bf16 via global_load_lds (linear chunks)
#pragma unroll
        for (int i = 0; i < 4; ++i) {
            int ci = wid + i * 4;
            int r = ci * 8 + (lane >> 3), c = (lane & 7) * 8;
            gload16(B + (size_t)(bn0 + r) * FEAT + k0 + c, smem + 16384 + ci * 1024);
        }
        __syncthreads();
#pragma unroll
        for (int kk = 0; kk < 64; kk += 32) {
            short8 a[4], b[4];
#pragma unroll
            for (int f = 0; f < 4; ++f) {
                a[f] = *(const short8*)(smem + (wm * 64 + f * 16 + lf) * 128 + (kk + ls * 8) * 2);
                b[f] = *(const short8*)(smem + 16384 + (wn * 64 + f * 16 + lf) * 128 + (kk + ls * 8) * 2);
            }
#pragma unroll
            for (int fm = 0; fm < 4; ++fm)
#pragma unroll
                for (int fn = 0; fn < 4; ++fn)
                    acc[fm][fn] = __builtin_amdgcn_mfma_f32_16x16x32_bf16(a[fm], b[fn], acc[fm][fn], 0, 0, 0);
        }
    }
    int tr = ls * 4, tc = lf;
    float sq[4][4] = {};
#pragma unroll
    for (int fn = 0; fn < 4; ++fn) {
        int col = bn0 + wn * 64 + fn * 16 + tc;
        float bb = bias[col];
#pragma unroll
        for (int fm = 0; fm < 4; ++fm) {
#pragma unroll
            for (int r = 0; r < 4; ++r) {
                int row = bm0 + wm * 64 + fm * 16 + tr + r;
                float v = acc[fm][fn][r] + bb;
                sq[fm][r] += v * v;
                if (row < NALL) {
                    int pr = (row % 100) * 10 + row / 100;
                    epb[(size_t)pr * FEAT + col] = f2bf(v);
                }
            }
        }
    }
    // psq partials: reduce over the 16 lf-lanes sharing a row, atomic per row-block
#pragma unroll
    for (int fm = 0; fm < 4; ++fm)
#pragma unroll
        for (int r = 0; r < 4; ++r) {
            float s = sq[fm][r];
            s += __shfl_xor(s, 1); s += __shfl_xor(s, 2);
            s += __shfl_xor(s, 4); s += __shfl_xor(s, 8);
            int row = bm0 + wm * 64 + fm * 16 + tr + r;
            if (lf == 0 && row < NALL) {
                int pr = (row % 100) * 10 + row / 100;
                atomicAdd(psq + pr, s);
            }
        }
}

// K3: main GEMM (16384 x 1040-effective x 1024) + fused sqrt + min-over-10.
// r10 geometry frozen (BM=128, BN=80, BK=64, 4 waves 4Mx1N, acc[2][5], 27KB LDS,
// 4 blocks/CU). Change: 13 N-tiles, last at bn0=920 (classes 92-99; overlap
// classes 92-95 written twice, identical values). Grid 128x13 = 1664.
__global__ __launch_bounds__(256, 4) void k_main(const unsigned short* __restrict__ xb,
                                                 const unsigned short* __restrict__ epb,
                                                 const float* __restrict__ xsq,
                                                 const float* __restrict__ psq,
                                                 float* __restrict__ out) {
    __shared__ __align__(16) char smem[27648];
    const int bid = blockIdx.x;                       // 1664 blocks
    const int swz = (bid & 7) * 208 + (bid >> 3);     // XCD swizzle (1664 % 8 == 0)
    const int bm0 = (swz / 13) * 128;
    const int nt  = swz % 13;
    const int bn0 = (nt < 12) ? nt * 80 : 920;
    const int cls0 = (nt < 12) ? nt * 8 : 92;
    const int tid = threadIdx.x, lane = tid & 63, wid = tid >> 6;
    const int ls = lane >> 4, lf = lane & 15;
    float* xsq_s = (float*)(smem + 26624);
    float* psq_s = (float*)(smem + 27136);
    if (tid < 128) xsq_s[tid] = xsq[bm0 + tid];
    if (tid < 80)  psq_s[tid] = psq[bn0 + tid];

    // staging (rule 21): lane (r=lane>>3, cb=lane&7) loads logical col block
    // (cb ^ r) so the linear LDS write lands at the swizzled slot.
    const int sr = lane >> 3, scb = lane & 7;
    const int scol = ((scb ^ sr) << 3);
    const unsigned short* aptr[4];
    const unsigned short* bptr[3];
#pragma unroll
    for (int i = 0; i < 4; ++i)
        aptr[i] = xb + (size_t)(bm0 + (wid + i * 4) * 8 + sr) * FEAT + scol;
#pragma unroll
    for (int j = 0; j < 3; ++j) {
        int cj = wid + j * 4;
        bptr[j] = epb + (size_t)(bn0 + (cj < 10 ? cj : 0) * 8 + sr) * FEAT + scol;
    }

    // swizzled read offsets: addr = row*128 + ((CB ^ (row&7)) << 4)
    int raA[2], raB[5];
#pragma unroll
    for (int f = 0; f < 2; ++f) raA[f] = (wid * 32 + f * 16 + lf) * 128;
#pragma unroll
    for (int f = 0; f < 5; ++f) raB[f] = 16384 + (f * 16 + lf) * 128;
    const int sw = lf & 7;

    f32x4 acc[2][5] = {};

    for (int t = 0; t < 16; ++t) {
        __syncthreads();   // previous tile's reads done before overwrite
#pragma unroll
        for (int i = 0; i < 4; ++i)
            gload16(aptr[i], smem + (wid + i * 4) * 1024);
#pragma unroll
        for (int j = 0; j < 3; ++j) {
            int cj = wid + j * 4;
            if (cj < 10) gload16(bptr[j], smem + 16384 + cj * 1024);
        }
#pragma unroll
        for (int i = 0; i < 4; ++i) aptr[i] += 64;
#pragma unroll
        for (int j = 0; j < 3; ++j) bptr[j] += 64;
        __syncthreads();   // drains vmcnt -> staged data visible
#pragma unroll
        for (int kk2 = 0; kk2 < 2; ++kk2) {
            const int off = (((kk2 * 4 + ls) ^ sw) << 4);
            short8 a[2], b[5];
#pragma unroll
            for (int f = 0; f < 2; ++f)
                a[f] = *(const short8*)(smem + raA[f] + off);
#pragma unroll
            for (int f = 0; f < 5; ++f)
                b[f] = *(const short8*)(smem + raB[f] + off);
#pragma unroll
            for (int fm = 0; fm < 2; ++fm)
#pragma unroll
                for (int fn = 0; fn < 5; ++fn)
                    acc[fm][fn] = __builtin_amdgcn_mfma_f32_16x16x32_bf16(a[fm], b[fn], acc[fm][fn], 0, 0, 0);
        }
    }

    // epilogue: d = sqrt(max(xsq - 2*dot + psq, 0)); min over groups of 10.
    float* dls = (float*)smem;
    const int tr = ls * 4;
#pragma unroll
    for (int p = 0; p < 2; ++p) {
        __syncthreads();
#pragma unroll
        for (int fn = 0; fn < 5; ++fn) {
            int col = fn * 16 + lf;
            float pq = psq_s[col];
#pragma unroll
            for (int r = 0; r < 4; ++r) {
                float d2 = xsq_s[wid * 32 + p * 16 + tr + r] - 2.f * acc[p][fn][r] + pq;
                dls[(wid * 16 + tr + r) * 81 + col] = sqrtf(fmaxf(d2, 0.f));
            }
        }
        __syncthreads();
#pragma unroll
        for (int i = 0; i < 2; ++i) {
            int task = tid + i * 256;      // 512 tasks: 64 rows x 8 classes
            int rr = task >> 3, cl = task & 7;
            float m = 1e30f;
#pragma unroll
            for (int j = 0; j < 10; ++j) m = fminf(m, dls[rr * 81 + cl * 10 + j]);
            int grow = bm0 + (rr >> 4) * 32 + p * 16 + (rr & 15);
            out[(size_t)grow * NCLS + cls0 + cl] = m;
        }
    }
}

extern "C" void kernel_launch(void* const* d_in, const int* in_sizes, int n_in,
                              void* d_out, int out_size, void* d_ws, size_t ws_size,
                              hipStream_t stream) {
    const float* x      = (const float*)d_in[0];
    const float* protos = (const float*)d_in[1];
    const float* enc_w  = (const float*)d_in[2];
    const float* enc_b  = (const float*)d_in[3];
    float* out = (float*)d_out;
    char* ws = (char*)d_ws;

    unsigned short* xb  = (unsigned short*)ws;                   // 16384*1024*2 = 33554432
    unsigned short* epb = (unsigned short*)(ws + 33554432);      // 1000*1024*2  (2MB slot)
    unsigned short* wtb = (unsigned short*)(ws + 35848192);      // 1024*1024*2  = 2097152
    float* xsq = (float*)(ws + 37945344);                        // 16384*4
    float* psq = (float*)(ws + 38010880);                        // 1000*4

    hipMemsetAsync(psq, 0, (size_t)NALL * 4, stream);            // atomics accumulate

    k_prep_x<<<4096, 256, 0, stream>>>(x, xb, xsq);
    k_transpose_w<<<dim3(32, 32), 256, 0, stream>>>(enc_w, wtb);
    k_enc<<<64, 256, 0, stream>>>(protos, wtb, enc_b, epb, psq);
    k_main<<<1664, 256, 0, stream>>>(xb, epb, xsq, psq, out);
}

// Round 12
// 101.657 us; speedup vs baseline: 1.1876x; 1.1876x over previous
//
#include <hip/hip_runtime.h>
#include <hip/hip_bf16.h>
#include <stdint.h>

#define FEAT 1024
#define NALL 1000
#define NCLS 100

typedef __attribute__((ext_vector_type(8))) short short8;
typedef __attribute__((ext_vector_type(4))) float f32x4;
typedef __attribute__((ext_vector_type(4))) unsigned short us4;

__device__ __forceinline__ unsigned short f2bf(float f) {
    union { float f; uint32_t u; } v; v.f = f;
    uint32_t u = v.u;
    return (unsigned short)((u + 0x7FFFu + ((u >> 16) & 1u)) >> 16);
}

__device__ __forceinline__ void gload16(const void* g, void* l) {
    __builtin_amdgcn_global_load_lds((__attribute__((address_space(1))) void*)g,
                                     (__attribute__((address_space(3))) void*)l,
                                     16, 0, 0);
}

// K1: x (16384x1024 f32) -> bf16, plus row sum-of-squares
__global__ __launch_bounds__(256) void k_prep_x(const float* __restrict__ x,
                                                unsigned short* __restrict__ xb,
                                                float* __restrict__ xsq) {
    int row = blockIdx.x * 4 + (threadIdx.x >> 6);
    int lane = threadIdx.x & 63;
    const float4* xr = (const float4*)(x + (size_t)row * FEAT);
    float s = 0.f;
#pragma unroll
    for (int i = 0; i < 4; ++i) {
        float4 v = xr[lane + i * 64];
        s += v.x * v.x + v.y * v.y + v.z * v.z + v.w * v.w;
        us4 o;
        o[0] = f2bf(v.x); o[1] = f2bf(v.y); o[2] = f2bf(v.z); o[3] = f2bf(v.w);
        *(us4*)(xb + (size_t)row * FEAT + (size_t)(lane + i * 64) * 4) = o;
    }
#pragma unroll
    for (int off = 32; off; off >>= 1) s += __shfl_xor(s, off);
    if (lane == 0) xsq[row] = s;
}

// K2a: protos (1000x1024 f32) -> bf16 padded to 1024 rows (pad = 0)
__global__ __launch_bounds__(256) void k_prep_protos(const float* __restrict__ p,
                                                     unsigned short* __restrict__ pb) {
    int row = blockIdx.x;
    int t = threadIdx.x;
    us4 o;
    if (row < NALL) {
        float4 v = ((const float4*)(p + (size_t)row * FEAT))[t];
        o[0] = f2bf(v.x); o[1] = f2bf(v.y); o[2] = f2bf(v.z); o[3] = f2bf(v.w);
    } else {
        o[0] = 0; o[1] = 0; o[2] = 0; o[3] = 0;
    }
    *(us4*)(pb + (size_t)row * FEAT + (size_t)t * 4) = o;
}

// K2b: enc_w (1024x1024 f32) -> transposed bf16 (wt[n][k] = enc_w[k][n])
__global__ __launch_bounds__(256) void k_transpose_w(const float* __restrict__ w,
                                                     unsigned short* __restrict__ wt) {
    __shared__ float tile[32][33];
    int bx = blockIdx.x, by = blockIdx.y;
    int tx = threadIdx.x & 31, ty = threadIdx.x >> 5;
#pragma unroll
    for (int i = 0; i < 4; ++i) {
        int r = by * 32 + ty + i * 8;
        tile[ty + i * 8][tx] = w[(size_t)r * FEAT + bx * 32 + tx];
    }
    __syncthreads();
#pragma unroll
    for (int i = 0; i < 4; ++i) {
        int r = bx * 32 + ty + i * 8;
        wt[(size_t)r * FEAT + by * 32 + tx] = f2bf(tile[tx][ty + i * 8]);
    }
}

// K2c: encoder GEMM: ep = protos @ enc_w + b (r10-proven, gload16 staging).
// Writes epb rows in class-major permuted order: n' = (n%100)*10 + n/100.
__global__ __launch_bounds__(256) void k_enc_gemm(const unsigned short* __restrict__ A,
                                                  const unsigned short* __restrict__ B,
                                                  const float* __restrict__ bias,
                                                  unsigned short* __restrict__ epb) {
    __shared__ __align__(16) char smem[32768];
    int bm0 = (blockIdx.x >> 3) * 128;
    int bn0 = (blockIdx.x & 7) * 128;
    int tid = threadIdx.x, lane = tid & 63, wid = tid >> 6;
    int wm = wid >> 1, wn = wid & 1;
    int ls = lane >> 4, lf = lane & 15;
    f32x4 acc[4][4] = {};
    for (int k0 = 0; k0 < FEAT; k0 += 64) {
        __syncthreads();
#pragma unroll
        for (int i = 0; i < 4; ++i) {
            int ci = wid + i * 4;
            int r = ci * 8 + (lane >> 3), c = (lane & 7) * 8;
            gload16(A + (size_t)(bm0 + r) * FEAT + k0 + c, smem + ci * 1024);
            gload16(B + (size_t)(bn0 + r) * FEAT + k0 + c, smem + 16384 + ci * 1024);
        }
        __syncthreads();
#pragma unroll
        for (int kk = 0; kk < 64; kk += 32) {
            short8 a[4], b[4];
#pragma unroll
            for (int f = 0; f < 4; ++f) {
                a[f] = *(const short8*)(smem + (wm * 64 + f * 16 + lf) * 128 + (kk + ls * 8) * 2);
                b[f] = *(const short8*)(smem + 16384 + (wn * 64 + f * 16 + lf) * 128 + (kk + ls * 8) * 2);
            }
#pragma unroll
            for (int fm = 0; fm < 4; ++fm)
#pragma unroll
                for (int fn = 0; fn < 4; ++fn)
                    acc[fm][fn] = __builtin_amdgcn_mfma_f32_16x16x32_bf16(a[fm], b[fn], acc[fm][fn], 0, 0, 0);
        }
    }
    int tr = ls * 4, tc = lf;
#pragma unroll
    for (int fn = 0; fn < 4; ++fn) {
        int col = bn0 + wn * 64 + fn * 16 + tc;
        float bb = bias[col];
#pragma unroll
        for (int fm = 0; fm < 4; ++fm) {
#pragma unroll
            for (int r = 0; r < 4; ++r) {
                int row = bm0 + wm * 64 + fm * 16 + tr + r;
                if (row < NALL) {
                    int pr = (row % 100) * 10 + row / 100;
                    epb[(size_t)pr * FEAT + col] = f2bf(acc[fm][fn][r] + bb);
                }
            }
        }
    }
}

// K2d: p_sq per (permuted) ep row, rows 0..999 only (k_main reads none past 1000)
__global__ __launch_bounds__(256) void k_psq(const unsigned short* __restrict__ epb,
                                             float* __restrict__ psq) {
    int row = blockIdx.x * 4 + (threadIdx.x >> 6);
    int lane = threadIdx.x & 63;
    if (row >= NALL) return;
    float s = 0.f;
    const short8* r8 = (const short8*)(epb + (size_t)row * FEAT);
#pragma unroll
    for (int i = 0; i < 2; ++i) {
        short8 v = r8[lane + i * 64];
#pragma unroll
        for (int j = 0; j < 8; ++j) {
            union { uint32_t u; float f; } c;
            c.u = ((uint32_t)(unsigned short)v[j]) << 16;
            s += c.f * c.f;
        }
    }
#pragma unroll
    for (int off = 32; off; off >>= 1) s += __shfl_xor(s, off);
    if (lane == 0) psq[row] = s;
}

// K3: main GEMM + fused sqrt + min-over-10 (r11 version, byte-identical).
// BM=128, BN=80, BK=64, 4 waves 4Mx1N, acc[2][5], 27KB LDS, 4 blocks/CU.
// 13 N-tiles, last at bn0=920 (classes 92-99; overlap cols written twice with
// identical values). Grid 128x13 = 1664.
__global__ __launch_bounds__(256, 4) void k_main(const unsigned short* __restrict__ xb,
                                                 const unsigned short* __restrict__ epb,
                                                 const float* __restrict__ xsq,
                                                 const float* __restrict__ psq,
                                                 float* __restrict__ out) {
    __shared__ __align__(16) char smem[27648];
    const int bid = blockIdx.x;                       // 1664 blocks
    const int swz = (bid & 7) * 208 + (bid >> 3);     // XCD swizzle (1664 % 8 == 0)
    const int bm0 = (swz / 13) * 128;
    const int nt  = swz % 13;
    const int bn0 = (nt < 12) ? nt * 80 : 920;
    const int cls0 = (nt < 12) ? nt * 8 : 92;
    const int tid = threadIdx.x, lane = tid & 63, wid = tid >> 6;
    const int ls = lane >> 4, lf = lane & 15;
    float* xsq_s = (float*)(smem + 26624);
    float* psq_s = (float*)(smem + 27136);
    if (tid < 128) xsq_s[tid] = xsq[bm0 + tid];
    if (tid < 80)  psq_s[tid] = psq[bn0 + tid];

    // staging (rule 21): lane (r=lane>>3, cb=lane&7) loads logical col block
    // (cb ^ r) so the linear LDS write lands at the swizzled slot.
    const int sr = lane >> 3, scb = lane & 7;
    const int scol = ((scb ^ sr) << 3);
    const unsigned short* aptr[4];
    const unsigned short* bptr[3];
#pragma unroll
    for (int i = 0; i < 4; ++i)
        aptr[i] = xb + (size_t)(bm0 + (wid + i * 4) * 8 + sr) * FEAT + scol;
#pragma unroll
    for (int j = 0; j < 3; ++j) {
        int cj = wid + j * 4;
        bptr[j] = epb + (size_t)(bn0 + (cj < 10 ? cj : 0) * 8 + sr) * FEAT + scol;
    }

    // swizzled read offsets: addr = row*128 + ((CB ^ (row&7)) << 4)
    int raA[2], raB[5];
#pragma unroll
    for (int f = 0; f < 2; ++f) raA[f] = (wid * 32 + f * 16 + lf) * 128;
#pragma unroll
    for (int f = 0; f < 5; ++f) raB[f] = 16384 + (f * 16 + lf) * 128;
    const int sw = lf & 7;

    f32x4 acc[2][5] = {};

    for (int t = 0; t < 16; ++t) {
        __syncthreads();   // previous tile's reads done before overwrite
#pragma unroll
        for (int i = 0; i < 4; ++i)
            gload16(aptr[i], smem + (wid + i * 4) * 1024);
#pragma unroll
        for (int j = 0; j < 3; ++j) {
            int cj = wid + j * 4;
            if (cj < 10) gload16(bptr[j], smem + 16384 + cj * 1024);
        }
#pragma unroll
        for (int i = 0; i < 4; ++i) aptr[i] += 64;
#pragma unroll
        for (int j = 0; j < 3; ++j) bptr[j] += 64;
        __syncthreads();   // drains vmcnt -> staged data visible
#pragma unroll
        for (int kk2 = 0; kk2 < 2; ++kk2) {
            const int off = (((kk2 * 4 + ls) ^ sw) << 4);
            short8 a[2], b[5];
#pragma unroll
            for (int f = 0; f < 2; ++f)
                a[f] = *(const short8*)(smem + raA[f] + off);
#pragma unroll
            for (int f = 0; f < 5; ++f)
                b[f] = *(const short8*)(smem + raB[f] + off);
#pragma unroll
            for (int fm = 0; fm < 2; ++fm)
#pragma unroll
                for (int fn = 0; fn < 5; ++fn)
                    acc[fm][fn] = __builtin_amdgcn_mfma_f32_16x16x32_bf16(a[fm], b[fn], acc[fm][fn], 0, 0, 0);
        }
    }

    // epilogue: d = sqrt(max(xsq - 2*dot + psq, 0)); min over groups of 10.
    float* dls = (float*)smem;
    const int tr = ls * 4;
#pragma unroll
    for (int p = 0; p < 2; ++p) {
        __syncthreads();
#pragma unroll
        for (int fn = 0; fn < 5; ++fn) {
            int col = fn * 16 + lf;
            float pq = psq_s[col];
#pragma unroll
            for (int r = 0; r < 4; ++r) {
                float d2 = xsq_s[wid * 32 + p * 16 + tr + r] - 2.f * acc[p][fn][r] + pq;
                dls[(wid * 16 + tr + r) * 81 + col] = sqrtf(fmaxf(d2, 0.f));
            }
        }
        __syncthreads();
#pragma unroll
        for (int i = 0; i < 2; ++i) {
            int task = tid + i * 256;      // 512 tasks: 64 rows x 8 classes
            int rr = task >> 3, cl = task & 7;
            float m = 1e30f;
#pragma unroll
            for (int j = 0; j < 10; ++j) m = fminf(m, dls[rr * 81 + cl * 10 + j]);
            int grow = bm0 + (rr >> 4) * 32 + p * 16 + (rr & 15);
            out[(size_t)grow * NCLS + cls0 + cl] = m;
        }
    }
}

extern "C" void kernel_launch(void* const* d_in, const int* in_sizes, int n_in,
                              void* d_out, int out_size, void* d_ws, size_t ws_size,
                              hipStream_t stream) {
    const float* x      = (const float*)d_in[0];
    const float* protos = (const float*)d_in[1];
    const float* enc_w  = (const float*)d_in[2];
    const float* enc_b  = (const float*)d_in[3];
    float* out = (float*)d_out;
    char* ws = (char*)d_ws;

    unsigned short* xb  = (unsigned short*)ws;                   // 16384*1024*2 = 33554432
    unsigned short* epb = (unsigned short*)(ws + 33554432);      // 1000*1024*2 (2MB slot)
    unsigned short* prb = (unsigned short*)(ws + 35651584);      // 1024*1024*2  = 2097152
    unsigned short* wtb = (unsigned short*)(ws + 37748736);      // 1024*1024*2  = 2097152
    float* xsq = (float*)(ws + 39845888);                        // 16384*4
    float* psq = (float*)(ws + 39911424);                        // 1000*4

    k_prep_x<<<4096, 256, 0, stream>>>(x, xb, xsq);
    k_prep_protos<<<1024, 256, 0, stream>>>(protos, prb);
    k_transpose_w<<<dim3(32, 32), 256, 0, stream>>>(enc_w, wtb);
    k_enc_gemm<<<64, 256, 0, stream>>>(prb, wtb, enc_b, epb);
    k_psq<<<250, 256, 0, stream>>>(epb, psq);
    k_main<<<1664, 256, 0, stream>>>(xb, epb, xsq, psq, out);
}